// Round 14
// baseline (299.060 us; speedup 1.0000x reference)
//
#include <hip/hip_runtime.h>
#include <math.h>

#define NN 26000
#define NE 208000
#define SCAN_CH 26        // ceil(NN/1024), compile-time
#define CNT_BLOCKS 813    // ceil(NE/256)

typedef __attribute__((ext_vector_type(8))) short bf16x8;
typedef __attribute__((ext_vector_type(4))) float f32x4;
typedef __attribute__((ext_vector_type(2))) float f32x2;
typedef unsigned char u8;

__device__ __forceinline__ float bf2f(ushort u){
  union { unsigned int i; float f; } w; w.i = ((unsigned int)u) << 16; return w.f;
}
__device__ __forceinline__ ushort f2bf(float f){
  union { float f; unsigned int i; } w; w.f = f;
  unsigned int u = w.i + 0x7fffu + ((w.i >> 16) & 1u);  // RNE
  return (ushort)(u >> 16);
}

// wbuf layout (ushort):
//   [0)      MT     [512][128]  M_h = Wq^h Wk^hT  (u-projection weights)
//   [65536)  wcT    [512][128]  wskip + skip_w
//   [131072) lin1T  [128][512]
//   [196608) vprojT [512][128]  BT for Wv
//   [262144) l2rT | [278528) l2nT | [294912) l3rT | [311296) l3nT
// ---------------- fused count + weight-prep (incl. M GEMM) ----------------
__global__ void cp_k(const int* __restrict__ dst, int* __restrict__ cnt,
                     const float* __restrict__ wq, const float* __restrict__ wk,
                     const float* __restrict__ wv, const float* __restrict__ bq,
                     const float* __restrict__ wskip, const float* __restrict__ skw,
                     const float* __restrict__ lin1w,
                     const float* __restrict__ l2r, const float* __restrict__ l2n,
                     const float* __restrict__ l3r, const float* __restrict__ l3n,
                     ushort* __restrict__ wbuf, float* __restrict__ bu){
  int b = blockIdx.x, t = threadIdx.x;
  if (b < CNT_BLOCKS){
    int e = b*256 + t;
    if (e < NE) atomicAdd(&cnt[dst[e]], 1);
    return;
  }
  b -= CNT_BLOCKS;
  if (b < 256){                       // MT[n*128+k] = sum_c Wq[k,h*128+c]*Wk[m,h*128+c]
    int idx = b*256 + t;
    int n = idx >> 7, k2 = idx & 127, h = n >> 7, m = n & 127;
    const float* wqr = wq + (size_t)k2*512 + h*128;
    const float* wkr = wk + (size_t)m*512 + h*128;
    float s = 0.f;
    for (int c = 0; c < 128; ++c) s = fmaf(wqr[c], wkr[c], s);
    wbuf[idx] = f2bf(s);
    return;
  }
  b -= 256;
  if (b < 2){                         // bias_u[n] = sum_c bq[h*128+c]*Wk[m,h*128+c]
    int n = b*256 + t;
    int h = n >> 7, m = n & 127;
    const float* wkr = wk + (size_t)m*512 + h*128;
    float s = 0.f;
    for (int c = 0; c < 128; ++c) s = fmaf(bq[h*128 + c], wkr[c], s);
    bu[n] = s;
    return;
  }
  b -= 2;
  if (b < 256){                       // vprojT[n*128+m] = Wv[m, n]
    int idx = b*256 + t;
    int n = idx >> 7, m = idx & 127;
    wbuf[196608 + idx] = f2bf(wv[(size_t)m*512 + n]);
    return;
  }
  b -= 256;
  if (b < 256){                       // wcT[n*128+k] = wskip[k,n]+skw[k,n]
    int idx = b*256 + t;
    int n = idx >> 7, k2 = idx & 127;
    wbuf[65536 + idx] = f2bf(wskip[(size_t)k2*512 + n] + skw[(size_t)k2*512 + n]);
    return;
  }
  b -= 256;
  if (b < 256){                       // lin1T[n*512+k] = lin1w[k,n]
    int idx = b*256 + t;
    int n = idx >> 9, k2 = idx & 511;
    wbuf[131072 + idx] = f2bf(lin1w[(size_t)k2*128 + n]);
    return;
  }
  b -= 256;
  {                                   // l2rT,l2nT,l3rT,l3nT
    int idx = b*256 + t;
    int sg = idx >> 14, loc = idx & 16383, n = loc >> 7, k2 = loc & 127;
    const float* w = (sg == 0) ? l2r : (sg == 1) ? l2n : (sg == 2) ? l3r : l3n;
    wbuf[262144 + idx] = f2bf(w[(size_t)k2*128 + n]);
  }
}

// ---------------- scan (single block, register-resident) ----------------
__global__ __launch_bounds__(1024) void scan_k(int* __restrict__ cnt_cur, int* __restrict__ off){
  int t = threadIdx.x;
  int base = t * SCAN_CH;
  int v[SCAN_CH];
  #pragma unroll
  for (int j = 0; j < SCAN_CH; ++j){
    int idx = base + j;
    v[j] = (idx < NN) ? cnt_cur[idx] : 0;
  }
  int s = 0;
  #pragma unroll
  for (int j = 0; j < SCAN_CH; ++j) s += v[j];
  __shared__ int ls[1024];
  ls[t] = s; __syncthreads();
  for (int ofs = 1; ofs < 1024; ofs <<= 1){
    int u = (t >= ofs) ? ls[t - ofs] : 0;
    __syncthreads();
    ls[t] += u;
    __syncthreads();
  }
  int run = (t == 0) ? 0 : ls[t-1];
  #pragma unroll
  for (int j = 0; j < SCAN_CH; ++j){
    int idx = base + j;
    if (idx < NN){
      off[idx] = run;
      cnt_cur[idx] = run;
      run += v[j];
    }
  }
  if (t == 1023) off[NN] = ls[1023];
}

__global__ void fill_k(const int* __restrict__ src, const int* __restrict__ dst,
                       int* __restrict__ cur, int* __restrict__ csrc, int E){
  int e = blockIdx.x*256 + threadIdx.x;
  if (e < E){
    int p = atomicAdd(&cur[dst[e]], 1);
    csrc[p] = src[e];
  }
}

// ---------------- fused layer 1: agg6 + GraphConv(6->128) + relu + fp8 cast -----
__global__ __launch_bounds__(256) void layer1_k(
    const float* __restrict__ x, const int* __restrict__ off,
    const int* __restrict__ csrc, const float* __restrict__ w1r,
    const float* __restrict__ w1n, const float* __restrict__ b1,
    ushort* __restrict__ h1, u8* __restrict__ h1f)
{
  __shared__ float aggs[2][6];
  int slot = threadIdx.x >> 7, c = threadIdx.x & 127;
  int i = blockIdx.x*2 + slot;
  if (c < 6){
    float s = 0.f;
    int e1 = off[i+1];
    for (int j = off[i]; j < e1; ++j) s += x[(size_t)csrc[j]*6 + c];
    aggs[slot][c] = s;
  }
  __syncthreads();
  float s = b1[c];
  #pragma unroll
  for (int f = 0; f < 6; ++f){
    s = fmaf(x[i*6+f],    w1r[f*128+c], s);
    s = fmaf(aggs[slot][f], w1n[f*128+c], s);
  }
  float r = fmaxf(s, 0.f);
  h1[(size_t)i*128 + c] = f2bf(r);
  unsigned int pk = __builtin_amdgcn_cvt_pk_fp8_f32(r, r, 0u, false);
  h1f[(size_t)i*128 + c] = (u8)(pk & 0xffu);
}

// ---------------- fused U|S GEMM: u -> fp8 | skip -> bf16 -----------------------
__global__ __launch_bounds__(256) void us_k(
    const ushort* __restrict__ A, const ushort* __restrict__ wbuf,
    const float* __restrict__ bu, const float* __restrict__ bskip,
    u8* __restrict__ cu, ushort* __restrict__ cs, int M)
{
  __shared__ ushort smem[2*128*72];          // As | Bs; reused as epilogue tile
  ushort* Asm = smem;
  ushort* Bsm = smem + 128*72;
  int tid  = threadIdx.x;
  int lane = tid & 63;
  int wid  = tid >> 6;
  int wr = wid >> 1, wc = wid & 1;
  int rowbase = blockIdx.y * 128;
  int seg = blockIdx.x >> 2;
  int colloc = (blockIdx.x & 3) * 128;
  const ushort* BT = wbuf + (seg ? 65536 : 0);
  const float* bias = seg ? bskip : bu;
  int lr = lane & 15, lk = (lane >> 4) * 8;

  f32x4 acc[4][4] = {};

  for (int k0 = 0; k0 < 128; k0 += 64){
    #pragma unroll
    for (int i = 0; i < 4; ++i){
      int c = tid + i*256;
      int r = c >> 3, col8 = (c & 7) * 8;
      int row = rowbase + r;
      bf16x8 av = (bf16x8)0;
      if (row < M) av = *reinterpret_cast<const bf16x8*>(A + (size_t)row*128 + k0 + col8);
      *reinterpret_cast<bf16x8*>(&Asm[r*72 + col8]) = av;
      *reinterpret_cast<bf16x8*>(&Bsm[r*72 + col8]) =
          *reinterpret_cast<const bf16x8*>(BT + (size_t)(colloc + r)*128 + k0 + col8);
    }
    __syncthreads();
    #pragma unroll
    for (int ks = 0; ks < 64; ks += 32){
      bf16x8 af[4], bfr[4];
      #pragma unroll
      for (int i = 0; i < 4; ++i)
        af[i] = *reinterpret_cast<const bf16x8*>(&Asm[(wr*64 + i*16 + lr)*72 + ks + lk]);
      #pragma unroll
      for (int j = 0; j < 4; ++j)
        bfr[j] = *reinterpret_cast<const bf16x8*>(&Bsm[(wc*64 + j*16 + lr)*72 + ks + lk]);
      #pragma unroll
      for (int i = 0; i < 4; ++i)
        #pragma unroll
        for (int j = 0; j < 4; ++j)
          acc[i][j] = __builtin_amdgcn_mfma_f32_16x16x32_bf16(af[i], bfr[j], acc[i][j], 0, 0, 0);
    }
    __syncthreads();
  }

  int rq = lane >> 4;
  #pragma unroll
  for (int i = 0; i < 4; ++i)
    #pragma unroll
    for (int r = 0; r < 4; ++r){
      int lrow = wr*64 + i*16 + rq*4 + r;
      #pragma unroll
      for (int j = 0; j < 4; ++j){
        int lcol = wc*64 + j*16 + lr;
        smem[lrow*136 + lcol] = f2bf(acc[i][j][r] + bias[colloc + lcol]);
      }
    }
  __syncthreads();

  if (seg == 0){
    #pragma unroll
    for (int t = tid; t < 2048; t += 256){
      int r = t >> 4, s8 = (t & 15) * 8;
      int row = rowbase + r;
      if (row < M){
        bf16x8 hv = *reinterpret_cast<const bf16x8*>(&smem[r*136 + s8]);
        unsigned int lo = 0, hi = 0;
        lo = __builtin_amdgcn_cvt_pk_fp8_f32(bf2f((ushort)hv[0]), bf2f((ushort)hv[1]), lo, false);
        lo = __builtin_amdgcn_cvt_pk_fp8_f32(bf2f((ushort)hv[2]), bf2f((ushort)hv[3]), lo, true);
        hi = __builtin_amdgcn_cvt_pk_fp8_f32(bf2f((ushort)hv[4]), bf2f((ushort)hv[5]), hi, false);
        hi = __builtin_amdgcn_cvt_pk_fp8_f32(bf2f((ushort)hv[6]), bf2f((ushort)hv[7]), hi, true);
        uint2 o; o.x = lo; o.y = hi;
        *reinterpret_cast<uint2*>(cu + (size_t)row*512 + colloc + s8) = o;
      }
    }
  } else {
    #pragma unroll
    for (int t = tid; t < 2048; t += 256){
      int r = t >> 4, s8 = (t & 15) * 8;
      int row = rowbase + r;
      if (row < M)
        *reinterpret_cast<bf16x8*>(cs + (size_t)row*512 + colloc + s8) =
            *reinterpret_cast<const bf16x8*>(&smem[r*136 + s8]);
    }
  }
}

// ---------------- attention: 16-lane group per head, 4-deep prefetch ------------
// outputs agg/d as fp8 (halves traffic into vl_k)
__global__ __launch_bounds__(256) void attn_k(
    const u8* __restrict__ u, const u8* __restrict__ h1f,
    u8* __restrict__ aggf, float* __restrict__ beta,
    const int* __restrict__ off, const int* __restrict__ csrc)
{
  int lane = threadIdx.x & 63;
  int i = blockIdx.x*4 + (threadIdx.x >> 6);
  int g = lane >> 4;
  int cb = (lane & 15) * 8;

  uint2 uv = *reinterpret_cast<const uint2*>(u + (size_t)i*512 + g*128 + cb);
  f32x2 u01 = __builtin_amdgcn_cvt_pk_f32_fp8(uv.x, false);
  f32x2 u23 = __builtin_amdgcn_cvt_pk_f32_fp8(uv.x, true);
  f32x2 u45 = __builtin_amdgcn_cvt_pk_f32_fp8(uv.y, false);
  f32x2 u67 = __builtin_amdgcn_cvt_pk_f32_fp8(uv.y, true);
  float uf[8] = {u01[0], u01[1], u23[0], u23[1], u45[0], u45[1], u67[0], u67[1]};

  float d = 0.f, agg[8] = {};
  int e0 = off[i], e1 = off[i+1];
  uint2 hA, hB, hC, hD;
  if (e0     < e1) hA = *reinterpret_cast<const uint2*>(h1f + (size_t)csrc[e0]*128 + cb);
  if (e0 + 1 < e1) hB = *reinterpret_cast<const uint2*>(h1f + (size_t)csrc[e0+1]*128 + cb);
  if (e0 + 2 < e1) hC = *reinterpret_cast<const uint2*>(h1f + (size_t)csrc[e0+2]*128 + cb);
  if (e0 + 3 < e1) hD = *reinterpret_cast<const uint2*>(h1f + (size_t)csrc[e0+3]*128 + cb);

  for (int j = e0; j < e1; ++j){
    uint2 hc = hA; hA = hB; hB = hC; hC = hD;
    if (j + 4 < e1) hD = *reinterpret_cast<const uint2*>(h1f + (size_t)csrc[j+4]*128 + cb);
    f32x2 h01 = __builtin_amdgcn_cvt_pk_f32_fp8(hc.x, false);
    f32x2 h23 = __builtin_amdgcn_cvt_pk_f32_fp8(hc.x, true);
    f32x2 h45 = __builtin_amdgcn_cvt_pk_f32_fp8(hc.y, false);
    f32x2 h67 = __builtin_amdgcn_cvt_pk_f32_fp8(hc.y, true);
    float hj[8] = {h01[0], h01[1], h23[0], h23[1], h45[0], h45[1], h67[0], h67[1]};
    float p = uf[0]*hj[0];
    #pragma unroll
    for (int c = 1; c < 8; ++c) p = fmaf(uf[c], hj[c], p);
    p += __shfl_xor(p, 1);
    p += __shfl_xor(p, 2);
    p += __shfl_xor(p, 4);
    p += __shfl_xor(p, 8);                       // intra-16-lane-group reduce
    float a = __expf(p * 0.08838834764831845f);  // logits tiny: no max-shift needed
    d += a;
    #pragma unroll
    for (int c = 0; c < 8; ++c) agg[c] = fmaf(a, hj[c], agg[c]);
  }
  float inv = (d > 0.f) ? 1.f/d : 0.f;
  unsigned int lo = 0, hi = 0;
  lo = __builtin_amdgcn_cvt_pk_fp8_f32(agg[0]*inv, agg[1]*inv, lo, false);
  lo = __builtin_amdgcn_cvt_pk_fp8_f32(agg[2]*inv, agg[3]*inv, lo, true);
  hi = __builtin_amdgcn_cvt_pk_fp8_f32(agg[4]*inv, agg[5]*inv, hi, false);
  hi = __builtin_amdgcn_cvt_pk_fp8_f32(agg[6]*inv, agg[7]*inv, hi, true);
  uint2 o; o.x = lo; o.y = hi;
  *reinterpret_cast<uint2*>(aggf + (size_t)i*512 + g*128 + cb) = o;
  if ((lane & 15) == 0) beta[i*4 + g] = (d > 0.f) ? 1.f : 0.f;
}

// ---------------- fused vproj + lin1: h3 = relu(h2 @ lin1 + b), h2 in LDS only --
// h2_h = relu(s_h + agg_h@Wv_h + bv_h*beta); acc3 += h2_h @ lin1_chunk_h.
__global__ __launch_bounds__(256) void vl_k(
    const u8* __restrict__ aggf, const ushort* __restrict__ vT,
    const ushort* __restrict__ lin1T, const float* __restrict__ bv,
    const float* __restrict__ beta, const ushort* __restrict__ s,
    const float* __restrict__ lin1b, ushort* __restrict__ h3, int M)
{
  __shared__ ushort As[64*136];   // agg head tile (bf16, full K=128)
  __shared__ ushort Bs[128*72];   // weight half-tile
  __shared__ ushort Hs[64*136];   // h2 head tile
  __shared__ float sbeta[64*4];
  int tid = threadIdx.x, lane = tid & 63, wid = tid >> 6;
  int wr = wid >> 1, wc = wid & 1;
  int rowbase = blockIdx.x * 64;
  int lr = lane & 15, lk = (lane >> 4) * 8, rq = lane >> 4;

  {
    int r = tid >> 2, h = tid & 3;
    int row = rowbase + r;
    sbeta[r*4 + h] = (row < M) ? beta[row*4 + h] : 0.f;
  }

  f32x4 acc3[2][4] = {};

  for (int h = 0; h < 4; ++h){
    // stage As = agg head h (fp8 -> bf16); last As readers were >=4 barriers ago
    #pragma unroll
    for (int it = 0; it < 4; ++it){
      int c = tid + it*256;            // 0..1023
      int r = c >> 4, col8 = (c & 15) * 8;
      int row = rowbase + r;
      bf16x8 av = (bf16x8)0;
      if (row < M){
        uint2 f8 = *reinterpret_cast<const uint2*>(aggf + (size_t)row*512 + h*128 + col8);
        f32x2 a01 = __builtin_amdgcn_cvt_pk_f32_fp8(f8.x, false);
        f32x2 a23 = __builtin_amdgcn_cvt_pk_f32_fp8(f8.x, true);
        f32x2 a45 = __builtin_amdgcn_cvt_pk_f32_fp8(f8.y, false);
        f32x2 a67 = __builtin_amdgcn_cvt_pk_f32_fp8(f8.y, true);
        av[0] = (short)f2bf(a01[0]); av[1] = (short)f2bf(a01[1]);
        av[2] = (short)f2bf(a23[0]); av[3] = (short)f2bf(a23[1]);
        av[4] = (short)f2bf(a45[0]); av[5] = (short)f2bf(a45[1]);
        av[6] = (short)f2bf(a67[0]); av[7] = (short)f2bf(a67[1]);
      }
      *reinterpret_cast<bf16x8*>(&As[r*136 + col8]) = av;
    }

    // GEMM1: acc1 = As @ vT_h^T (K=128, two 64-halves through Bs)
    f32x4 acc1[2][4] = {};
    #pragma unroll
    for (int k0 = 0; k0 < 128; k0 += 64){
      __syncthreads();                 // As staged / prior Bs readers done
      #pragma unroll
      for (int it = 0; it < 4; ++it){
        int c = tid + it*256;          // Bs: 128 rows x 64 k
        int r = c >> 3, col8 = (c & 7) * 8;
        *reinterpret_cast<bf16x8*>(&Bs[r*72 + col8]) =
            *reinterpret_cast<const bf16x8*>(vT + (size_t)(h*128 + r)*128 + k0 + col8);
      }
      __syncthreads();
      #pragma unroll
      for (int ks = 0; ks < 64; ks += 32){
        bf16x8 af[2], bfr[4];
        #pragma unroll
        for (int i = 0; i < 2; ++i)
          af[i] = *reinterpret_cast<const bf16x8*>(&As[(wr*32 + i*16 + lr)*136 + k0 + ks + lk]);
        #pragma unroll
        for (int j = 0; j < 4; ++j)
          bfr[j] = *reinterpret_cast<const bf16x8*>(&Bs[(wc*64 + j*16 + lr)*72 + ks + lk]);
        #pragma unroll
        for (int i = 0; i < 2; ++i)
          #pragma unroll
          for (int j = 0; j < 4; ++j)
            acc1[i][j] = __builtin_amdgcn_mfma_f32_16x16x32_bf16(af[i], bfr[j], acc1[i][j], 0, 0, 0);
      }
    }

    // epilogue GEMM1 -> Hs = relu(s + acc1 + bv*beta)   (Hs readers >=2 barriers ago)
    #pragma unroll
    for (int i = 0; i < 2; ++i)
      #pragma unroll
      for (int r = 0; r < 4; ++r){
        int lrow = wr*32 + i*16 + rq*4 + r;
        int row = rowbase + lrow;
        #pragma unroll
        for (int j = 0; j < 4; ++j){
          int lcol = wc*64 + j*16 + lr;
          float sv = (row < M) ? bf2f(s[(size_t)row*512 + h*128 + lcol]) : 0.f;
          float v = fmaxf(sv + acc1[i][j][r] + bv[h*128 + lcol]*sbeta[lrow*4 + h], 0.f);
          Hs[lrow*136 + lcol] = f2bf(v);
        }
      }

    // GEMM2: acc3 += Hs @ lin1_chunk_h (K cols h*128..h*128+127)
    #pragma unroll
    for (int k0 = 0; k0 < 128; k0 += 64){
      __syncthreads();                 // Hs written / prior Bs readers done
      #pragma unroll
      for (int it = 0; it < 4; ++it){
        int c = tid + it*256;
        int r = c >> 3, col8 = (c & 7) * 8;
        *reinterpret_cast<bf16x8*>(&Bs[r*72 + col8]) =
            *reinterpret_cast<const bf16x8*>(lin1T + (size_t)r*512 + h*128 + k0 + col8);
      }
      __syncthreads();
      #pragma unroll
      for (int ks = 0; ks < 64; ks += 32){
        bf16x8 af[2], bfr[4];
        #pragma unroll
        for (int i = 0; i < 2; ++i)
          af[i] = *reinterpret_cast<const bf16x8*>(&Hs[(wr*32 + i*16 + lr)*136 + k0 + ks + lk]);
        #pragma unroll
        for (int j = 0; j < 4; ++j)
          bfr[j] = *reinterpret_cast<const bf16x8*>(&Bs[(wc*64 + j*16 + lr)*72 + ks + lk]);
        #pragma unroll
        for (int i = 0; i < 2; ++i)
          #pragma unroll
          for (int j = 0; j < 4; ++j)
            acc3[i][j] = __builtin_amdgcn_mfma_f32_16x16x32_bf16(af[i], bfr[j], acc3[i][j], 0, 0, 0);
      }
    }
  }

  // final: h3 = relu(acc3 + lin1b)
  #pragma unroll
  for (int i = 0; i < 2; ++i)
    #pragma unroll
    for (int r = 0; r < 4; ++r){
      int row = rowbase + wr*32 + i*16 + rq*4 + r;
      if (row >= M) continue;
      #pragma unroll
      for (int j = 0; j < 4; ++j){
        int col = wc*64 + j*16 + lr;
        h3[(size_t)row*128 + col] = f2bf(fmaxf(acc3[i][j][r] + lin1b[col], 0.f));
      }
    }
}

// ---------------- fused GraphConv: out = relu(h@Wr + agg(h)@Wn + b + h) ---------
__global__ __launch_bounds__(256) void gconv_k(
    const ushort* __restrict__ h, const ushort* __restrict__ WrT,
    const ushort* __restrict__ WnT, const float* __restrict__ bias,
    const int* __restrict__ off, const int* __restrict__ csrc,
    ushort* __restrict__ out, int M)
{
  __shared__ ushort As1[64][136];
  __shared__ ushort As2[64][136];
  int tid = threadIdx.x, lane = tid & 63, wid = tid >> 6;
  int wr = wid >> 1, wc = wid & 1;
  int rowbase = blockIdx.x * 64;
  int lr = lane & 15, lk = (lane >> 4) * 8;

  #pragma unroll
  for (int it = 0; it < 4; ++it){
    int c = tid + it*256;
    int r = c >> 4, col8 = (c & 15) * 8;
    int row = rowbase + r;
    bf16x8 av = (bf16x8)0;
    if (row < M) av = *reinterpret_cast<const bf16x8*>(h + (size_t)row*128 + col8);
    *reinterpret_cast<bf16x8*>(&As1[r][col8]) = av;
  }
  {
    int r = tid >> 2, sl = tid & 3;
    int row = rowbase + r;
    float a[32] = {};
    if (row < M){
      int e1 = off[row+1];
      for (int j = off[row]; j < e1; ++j){
        const ushort* hp = h + (size_t)csrc[j]*128 + sl*32;
        #pragma unroll
        for (int u = 0; u < 4; ++u){
          bf16x8 hv = *reinterpret_cast<const bf16x8*>(hp + u*8);
          #pragma unroll
          for (int p = 0; p < 8; ++p) a[u*8+p] += bf2f((ushort)hv[p]);
        }
      }
    }
    #pragma unroll
    for (int u = 0; u < 4; ++u){
      bf16x8 o;
      #pragma unroll
      for (int p = 0; p < 8; ++p) o[p] = (short)f2bf(a[u*8+p]);
      *reinterpret_cast<bf16x8*>(&As2[r][sl*32 + u*8]) = o;
    }
  }
  __syncthreads();

  f32x4 acc[2][4] = {};
  #pragma unroll
  for (int pass = 0; pass < 2; ++pass){
    const ushort* BT = pass ? WnT : WrT;
    #pragma unroll
    for (int kk = 0; kk < 128; kk += 32){
      bf16x8 af[2], bfr[4];
      #pragma unroll
      for (int i = 0; i < 2; ++i)
        af[i] = pass
          ? *reinterpret_cast<const bf16x8*>(&As2[wr*32 + i*16 + lr][kk + lk])
          : *reinterpret_cast<const bf16x8*>(&As1[wr*32 + i*16 + lr][kk + lk]);
      #pragma unroll
      for (int j = 0; j < 4; ++j)
        bfr[j] = *reinterpret_cast<const bf16x8*>(
            BT + (size_t)(wc*64 + j*16 + lr)*128 + kk + lk);
      #pragma unroll
      for (int i = 0; i < 2; ++i)
        #pragma unroll
        for (int j = 0; j < 4; ++j)
          acc[i][j] = __builtin_amdgcn_mfma_f32_16x16x32_bf16(af[i], bfr[j], acc[i][j], 0, 0, 0);
    }
  }

  int rq = lane >> 4;
  #pragma unroll
  for (int i = 0; i < 2; ++i){
    #pragma unroll
    for (int r = 0; r < 4; ++r){
      int lrow = wr*32 + i*16 + rq*4 + r;
      int row = rowbase + lrow;
      if (row >= M) continue;
      #pragma unroll
      for (int j = 0; j < 4; ++j){
        int col = wc*64 + j*16 + lr;
        float v = acc[i][j][r] + bias[col] + bf2f(As1[lrow][col]);
        out[(size_t)row*128 + col] = f2bf(fmaxf(v, 0.f));
      }
    }
  }
}

// ---------------- pooling stage 1: partial row sums ----------------
__global__ __launch_bounds__(256) void fc1_k(const ushort* __restrict__ h,
                                             float* __restrict__ partial){
  int s = blockIdx.x, c0 = blockIdx.y;
  int t = threadIdx.x;
  int c = t & 127, g = t >> 7;
  float sum = 0.f;
  int rend = (c0 + 1) * 125;
  for (int r = c0*125 + g; r < rend; r += 2)
    sum += bf2f(h[((size_t)s*1625 + r)*128 + c]);
  __shared__ float zs[2][128];
  zs[g][c] = sum; __syncthreads();
  if (g == 0) partial[((size_t)s*13 + c0)*128 + c] = zs[0][c] + zs[1][c];
}

// ---------------- pooling stage 2 + classifier ----------------
__global__ __launch_bounds__(128) void fc2_k(const float* __restrict__ partial,
    const float* __restrict__ fcw, const float* __restrict__ fcb,
    float* __restrict__ out)
{
  int s = blockIdx.x;
  int c = threadIdx.x;
  float z = 0.f;
  #pragma unroll
  for (int p = 0; p < 13; ++p) z += partial[((size_t)s*13 + p)*128 + c];
  __shared__ float zs[128];
  zs[c] = z * (1.0f/1625.0f);
  __syncthreads();
  if (c < 7){
    float o = fcb[c];
    for (int k2 = 0; k2 < 128; ++k2) o = fmaf(zs[k2], fcw[k2*7 + c], o);
    out[s*7 + c] = o;
  }
}

// ---------------- launcher ----------------
extern "C" void kernel_launch(void* const* d_in, const int* in_sizes, int n_in,
                              void* d_out, int out_size, void* d_ws, size_t ws_size,
                              hipStream_t stream)
{
  const float* x     = (const float*)d_in[0];
  const int*   ei    = (const int*)  d_in[1];
  const float* w1r   = (const float*)d_in[3];
  const float* w1n   = (const float*)d_in[4];
  const float* b1    = (const float*)d_in[5];
  const float* wq    = (const float*)d_in[6];
  const float* bq    = (const float*)d_in[7];
  const float* wk    = (const float*)d_in[8];
  const float* wv    = (const float*)d_in[10];
  const float* bv    = (const float*)d_in[11];
  const float* wskip = (const float*)d_in[12];
  const float* bskip = (const float*)d_in[13];
  const float* skw   = (const float*)d_in[14];
  const float* lin1w = (const float*)d_in[15];
  const float* lin1b = (const float*)d_in[16];
  const float* l2r   = (const float*)d_in[17];
  const float* l2n   = (const float*)d_in[18];
  const float* l2b   = (const float*)d_in[19];
  const float* l3r   = (const float*)d_in[20];
  const float* l3n   = (const float*)d_in[21];
  const float* l3b   = (const float*)d_in[22];
  const float* fcw   = (const float*)d_in[23];
  const float* fcb   = (const float*)d_in[24];
  float* out = (float*)d_out;

  const int* src = ei;
  const int* dst = ei + NE;

  char* base = (char*)d_ws;
  size_t o = 0;
  auto alloc = [&](size_t bytes) -> void* {
    o = (o + 255) & ~(size_t)255;
    void* p = base + o; o += bytes; return p;
  };
  int*    cnt     = (int*)   alloc((size_t)NN*4);
  int*    off     = (int*)   alloc((size_t)(NN+1)*4);
  int*    csrc    = (int*)   alloc((size_t)NE*4);
  float*  partial = (float*) alloc((size_t)16*13*128*4);
  float*  bu      = (float*) alloc((size_t)512*4);
  float*  beta    = (float*) alloc((size_t)NN*4*4);
  ushort* h1      = (ushort*)alloc((size_t)NN*128*2);
  u8*     h1f     = (u8*)    alloc((size_t)NN*128);
  ushort* wbuf    = (ushort*)alloc((size_t)327680*2);
  u8*     bufU8   = (u8*)    alloc((size_t)NN*512);     // fp8 u
  u8*     aggf    = (u8*)    alloc((size_t)NN*512);     // fp8 agg/d
  ushort* bufS    = (ushort*)alloc((size_t)NN*512*2);   // skip -> (dead) -> h5
  ushort* hbuf    = (ushort*)alloc((size_t)NN*256*2);   // h3 | h4
  (void)ws_size; (void)in_sizes; (void)n_in; (void)out_size;

  const ushort* lin1T = wbuf + 131072;
  const ushort* vT    = wbuf + 196608;
  const ushort* l2rT  = wbuf + 262144;
  const ushort* l2nT  = wbuf + 278528;
  const ushort* l3rT  = wbuf + 294912;
  const ushort* l3nT  = wbuf + 311296;

  ushort* h3 = hbuf;
  ushort* h4 = hbuf + (size_t)NN*128;
  ushort* h5 = bufS;   // skip dead after vl_k

  // CSR + weight prep (incl. M = Wq Wk^T per head)
  hipMemsetAsync(cnt, 0, (size_t)NN*4, stream);
  cp_k<<<CNT_BLOCKS + 256 + 2 + 256 + 256 + 256 + 256, 256, 0, stream>>>(
      dst, cnt, wq, wk, wv, bq, wskip, skw, lin1w, l2r, l2n, l3r, l3n, wbuf, bu);
  scan_k<<<1, 1024, 0, stream>>>(cnt, off);
  fill_k<<<(NE+255)/256, 256, 0, stream>>>(src, dst, cnt, csrc, NE);

  // layer 1 (fused agg + conv + fp8 cast)
  layer1_k<<<NN/2, 256, 0, stream>>>(x, off, csrc, w1r, w1n, b1, h1, h1f);

  // u | skip projection
  {
    dim3 g(8, (NN+127)/128);
    us_k<<<g, 256, 0, stream>>>(h1, wbuf, bu, bskip, bufU8, bufS, NN);
  }

  // attention: logits via u.h1, aggregate h1 -> aggf (fp8), beta flags
  attn_k<<<NN/4, 256, 0, stream>>>(bufU8, h1f, aggf, beta, off, csrc);

  // fused vproj + lin1 -> h3 (h2 lives only in LDS)
  vl_k<<<(NN+63)/64, 256, 0, stream>>>(aggf, vT, lin1T, bv, beta, bufS, lin1b, h3, NN);

  // GraphConv residual layers
  gconv_k<<<(NN+63)/64, 256, 0, stream>>>(h3, l2rT, l2nT, l2b, off, csrc, h4, NN);
  gconv_k<<<(NN+63)/64, 256, 0, stream>>>(h4, l3rT, l3nT, l3b, off, csrc, h5, NN);

  // pool + frame mean + classify
  {
    dim3 g1(16, 13);
    fc1_k<<<g1, 256, 0, stream>>>(h5, partial);
    fc2_k<<<16, 128, 0, stream>>>(partial, fcw, fcb, out);
  }
}

// Round 15
// 292.680 us; speedup vs baseline: 1.0218x; 1.0218x over previous
//
#include <hip/hip_runtime.h>
#include <math.h>

#define NN 26000
#define NE 208000
#define SCAN_CH 26        // ceil(NN/1024), compile-time
#define CNT_BLOCKS 813    // ceil(NE/256)

typedef __attribute__((ext_vector_type(8))) short bf16x8;
typedef __attribute__((ext_vector_type(4))) float f32x4;
typedef __attribute__((ext_vector_type(2))) float f32x2;
typedef unsigned char u8;

__device__ __forceinline__ float bf2f(ushort u){
  union { unsigned int i; float f; } w; w.i = ((unsigned int)u) << 16; return w.f;
}
__device__ __forceinline__ ushort f2bf(float f){
  union { float f; unsigned int i; } w; w.f = f;
  unsigned int u = w.i + 0x7fffu + ((w.i >> 16) & 1u);  // RNE
  return (ushort)(u >> 16);
}

// wbuf layout (ushort):
//   [0)      MT     [512][128]  M_h = Wq^h Wk^hT  (written by mt_k)
//   [65536)  wcT    [512][128]  wskip + skip_w
//   [131072) lin1T  [128][512]
//   [196608) vprojT [512][128]
//   [262144) l2rT | [278528) l2nT | [294912) l3rT | [311296) l3nT

// ---------------- MT GEMM: M_h = Wk_h . Wq_h^T (MFMA, coalesced) + bias_u -------
__global__ __launch_bounds__(256) void mt_k(
    const float* __restrict__ wq, const float* __restrict__ wk,
    const float* __restrict__ bq, ushort* __restrict__ MT,
    float* __restrict__ bu)
{
  __shared__ ushort Ak[128*136];   // Wk_h rows (b index)
  __shared__ ushort Bq[128*136];   // Wq_h rows (a index)
  __shared__ float bqs[128];
  int h = blockIdx.x;
  int tid = threadIdx.x, lane = tid & 63, wid = tid >> 6;
  int lr = lane & 15, lk = (lane >> 4)*8, rq = lane >> 4;

  #pragma unroll
  for (int it = 0; it < 16; ++it){
    int q4 = tid + it*256;           // 0..4095 float4 groups
    int m = q4 >> 5, c4 = (q4 & 31) * 4;
    float4 kv4 = *reinterpret_cast<const float4*>(wk + (size_t)m*512 + h*128 + c4);
    float4 qv4 = *reinterpret_cast<const float4*>(wq + (size_t)m*512 + h*128 + c4);
    ushort4 ko, qo;
    ko.x = f2bf(kv4.x); ko.y = f2bf(kv4.y); ko.z = f2bf(kv4.z); ko.w = f2bf(kv4.w);
    qo.x = f2bf(qv4.x); qo.y = f2bf(qv4.y); qo.z = f2bf(qv4.z); qo.w = f2bf(qv4.w);
    *reinterpret_cast<ushort4*>(&Ak[m*136 + c4]) = ko;
    *reinterpret_cast<ushort4*>(&Bq[m*136 + c4]) = qo;
  }
  if (tid < 128) bqs[tid] = bq[h*128 + tid];
  __syncthreads();

  f32x4 acc[2][8] = {};
  #pragma unroll
  for (int kk = 0; kk < 128; kk += 32){
    bf16x8 af[2], bfr[8];
    #pragma unroll
    for (int i = 0; i < 2; ++i)
      af[i] = *reinterpret_cast<const bf16x8*>(&Ak[(wid*32 + i*16 + lr)*136 + kk + lk]);
    #pragma unroll
    for (int j = 0; j < 8; ++j)
      bfr[j] = *reinterpret_cast<const bf16x8*>(&Bq[(j*16 + lr)*136 + kk + lk]);
    #pragma unroll
    for (int i = 0; i < 2; ++i)
      #pragma unroll
      for (int j = 0; j < 8; ++j)
        acc[i][j] = __builtin_amdgcn_mfma_f32_16x16x32_bf16(af[i], bfr[j], acc[i][j], 0, 0, 0);
  }

  // MT[(h*128 + b)*128 + a]
  #pragma unroll
  for (int i = 0; i < 2; ++i)
    #pragma unroll
    for (int r = 0; r < 4; ++r){
      int b = wid*32 + i*16 + rq*4 + r;
      #pragma unroll
      for (int j = 0; j < 8; ++j){
        int a = j*16 + lr;
        MT[(size_t)(h*128 + b)*128 + a] = f2bf(acc[i][j][r]);
      }
    }
  // bias_u[h*128+m] = sum_c bq_h[c] * Wk_h[m][c]
  if (tid < 128){
    float s = 0.f;
    #pragma unroll 8
    for (int c = 0; c < 128; ++c) s = fmaf(bqs[c], bf2f(Ak[tid*136 + c]), s);
    bu[h*128 + tid] = s;
  }
}

// ---------------- fused count + weight-prep (transposes only) ----------------
__global__ void cp_k(const int* __restrict__ dst, int* __restrict__ cnt,
                     const float* __restrict__ wv, const float* __restrict__ wskip,
                     const float* __restrict__ skw, const float* __restrict__ lin1w,
                     const float* __restrict__ l2r, const float* __restrict__ l2n,
                     const float* __restrict__ l3r, const float* __restrict__ l3n,
                     ushort* __restrict__ wbuf){
  int b = blockIdx.x, t = threadIdx.x;
  if (b < CNT_BLOCKS){
    int e = b*256 + t;
    if (e < NE) atomicAdd(&cnt[dst[e]], 1);
    return;
  }
  b -= CNT_BLOCKS;
  if (b < 256){                       // vprojT[n*128+m] = Wv[m, n]
    int idx = b*256 + t;
    int n = idx >> 7, m = idx & 127;
    wbuf[196608 + idx] = f2bf(wv[(size_t)m*512 + n]);
    return;
  }
  b -= 256;
  if (b < 256){                       // wcT[n*128+k] = wskip[k,n]+skw[k,n]
    int idx = b*256 + t;
    int n = idx >> 7, k2 = idx & 127;
    wbuf[65536 + idx] = f2bf(wskip[(size_t)k2*512 + n] + skw[(size_t)k2*512 + n]);
    return;
  }
  b -= 256;
  if (b < 256){                       // lin1T[n*512+k] = lin1w[k,n]
    int idx = b*256 + t;
    int n = idx >> 9, k2 = idx & 511;
    wbuf[131072 + idx] = f2bf(lin1w[(size_t)k2*128 + n]);
    return;
  }
  b -= 256;
  {                                   // l2rT,l2nT,l3rT,l3nT
    int idx = b*256 + t;
    int sg = idx >> 14, loc = idx & 16383, n = loc >> 7, k2 = loc & 127;
    const float* w = (sg == 0) ? l2r : (sg == 1) ? l2n : (sg == 2) ? l3r : l3n;
    wbuf[262144 + idx] = f2bf(w[(size_t)k2*128 + n]);
  }
}

// ---------------- scan (single block, register-resident) ----------------
__global__ __launch_bounds__(1024) void scan_k(int* __restrict__ cnt_cur, int* __restrict__ off){
  int t = threadIdx.x;
  int base = t * SCAN_CH;
  int v[SCAN_CH];
  #pragma unroll
  for (int j = 0; j < SCAN_CH; ++j){
    int idx = base + j;
    v[j] = (idx < NN) ? cnt_cur[idx] : 0;
  }
  int s = 0;
  #pragma unroll
  for (int j = 0; j < SCAN_CH; ++j) s += v[j];
  __shared__ int ls[1024];
  ls[t] = s; __syncthreads();
  for (int ofs = 1; ofs < 1024; ofs <<= 1){
    int u = (t >= ofs) ? ls[t - ofs] : 0;
    __syncthreads();
    ls[t] += u;
    __syncthreads();
  }
  int run = (t == 0) ? 0 : ls[t-1];
  #pragma unroll
  for (int j = 0; j < SCAN_CH; ++j){
    int idx = base + j;
    if (idx < NN){
      off[idx] = run;
      cnt_cur[idx] = run;
      run += v[j];
    }
  }
  if (t == 1023) off[NN] = ls[1023];
}

__global__ void fill_k(const int* __restrict__ src, const int* __restrict__ dst,
                       int* __restrict__ cur, int* __restrict__ csrc, int E){
  int e = blockIdx.x*256 + threadIdx.x;
  if (e < E){
    int p = atomicAdd(&cur[dst[e]], 1);
    csrc[p] = src[e];
  }
}

// ---------------- fused layer 1: agg6 + GraphConv(6->128) + relu + fp8 cast -----
__global__ __launch_bounds__(256) void layer1_k(
    const float* __restrict__ x, const int* __restrict__ off,
    const int* __restrict__ csrc, const float* __restrict__ w1r,
    const float* __restrict__ w1n, const float* __restrict__ b1,
    ushort* __restrict__ h1, u8* __restrict__ h1f)
{
  __shared__ float aggs[2][6];
  int slot = threadIdx.x >> 7, c = threadIdx.x & 127;
  int i = blockIdx.x*2 + slot;
  if (c < 6){
    float s = 0.f;
    int e1 = off[i+1];
    for (int j = off[i]; j < e1; ++j) s += x[(size_t)csrc[j]*6 + c];
    aggs[slot][c] = s;
  }
  __syncthreads();
  float s = b1[c];
  #pragma unroll
  for (int f = 0; f < 6; ++f){
    s = fmaf(x[i*6+f],    w1r[f*128+c], s);
    s = fmaf(aggs[slot][f], w1n[f*128+c], s);
  }
  float r = fmaxf(s, 0.f);
  h1[(size_t)i*128 + c] = f2bf(r);
  unsigned int pk = __builtin_amdgcn_cvt_pk_fp8_f32(r, r, 0u, false);
  h1f[(size_t)i*128 + c] = (u8)(pk & 0xffu);
}

// ---------------- fused U|S GEMM: u -> fp8 | skip -> bf16 -----------------------
__global__ __launch_bounds__(256) void us_k(
    const ushort* __restrict__ A, const ushort* __restrict__ wbuf,
    const float* __restrict__ bu, const float* __restrict__ bskip,
    u8* __restrict__ cu, ushort* __restrict__ cs, int M)
{
  __shared__ ushort smem[2*128*72];          // As | Bs; reused as epilogue tile
  ushort* Asm = smem;
  ushort* Bsm = smem + 128*72;
  int tid  = threadIdx.x;
  int lane = tid & 63;
  int wid  = tid >> 6;
  int wr = wid >> 1, wc = wid & 1;
  int rowbase = blockIdx.y * 128;
  int seg = blockIdx.x >> 2;
  int colloc = (blockIdx.x & 3) * 128;
  const ushort* BT = wbuf + (seg ? 65536 : 0);
  const float* bias = seg ? bskip : bu;
  int lr = lane & 15, lk = (lane >> 4) * 8;

  f32x4 acc[4][4] = {};

  for (int k0 = 0; k0 < 128; k0 += 64){
    #pragma unroll
    for (int i = 0; i < 4; ++i){
      int c = tid + i*256;
      int r = c >> 3, col8 = (c & 7) * 8;
      int row = rowbase + r;
      bf16x8 av = (bf16x8)0;
      if (row < M) av = *reinterpret_cast<const bf16x8*>(A + (size_t)row*128 + k0 + col8);
      *reinterpret_cast<bf16x8*>(&Asm[r*72 + col8]) = av;
      *reinterpret_cast<bf16x8*>(&Bsm[r*72 + col8]) =
          *reinterpret_cast<const bf16x8*>(BT + (size_t)(colloc + r)*128 + k0 + col8);
    }
    __syncthreads();
    #pragma unroll
    for (int ks = 0; ks < 64; ks += 32){
      bf16x8 af[4], bfr[4];
      #pragma unroll
      for (int i = 0; i < 4; ++i)
        af[i] = *reinterpret_cast<const bf16x8*>(&Asm[(wr*64 + i*16 + lr)*72 + ks + lk]);
      #pragma unroll
      for (int j = 0; j < 4; ++j)
        bfr[j] = *reinterpret_cast<const bf16x8*>(&Bsm[(wc*64 + j*16 + lr)*72 + ks + lk]);
      #pragma unroll
      for (int i = 0; i < 4; ++i)
        #pragma unroll
        for (int j = 0; j < 4; ++j)
          acc[i][j] = __builtin_amdgcn_mfma_f32_16x16x32_bf16(af[i], bfr[j], acc[i][j], 0, 0, 0);
    }
    __syncthreads();
  }

  int rq = lane >> 4;
  #pragma unroll
  for (int i = 0; i < 4; ++i)
    #pragma unroll
    for (int r = 0; r < 4; ++r){
      int lrow = wr*64 + i*16 + rq*4 + r;
      #pragma unroll
      for (int j = 0; j < 4; ++j){
        int lcol = wc*64 + j*16 + lr;
        smem[lrow*136 + lcol] = f2bf(acc[i][j][r] + bias[colloc + lcol]);
      }
    }
  __syncthreads();

  if (seg == 0){
    #pragma unroll
    for (int t = tid; t < 2048; t += 256){
      int r = t >> 4, s8 = (t & 15) * 8;
      int row = rowbase + r;
      if (row < M){
        bf16x8 hv = *reinterpret_cast<const bf16x8*>(&smem[r*136 + s8]);
        unsigned int lo = 0, hi = 0;
        lo = __builtin_amdgcn_cvt_pk_fp8_f32(bf2f((ushort)hv[0]), bf2f((ushort)hv[1]), lo, false);
        lo = __builtin_amdgcn_cvt_pk_fp8_f32(bf2f((ushort)hv[2]), bf2f((ushort)hv[3]), lo, true);
        hi = __builtin_amdgcn_cvt_pk_fp8_f32(bf2f((ushort)hv[4]), bf2f((ushort)hv[5]), hi, false);
        hi = __builtin_amdgcn_cvt_pk_fp8_f32(bf2f((ushort)hv[6]), bf2f((ushort)hv[7]), hi, true);
        uint2 o; o.x = lo; o.y = hi;
        *reinterpret_cast<uint2*>(cu + (size_t)row*512 + colloc + s8) = o;
      }
    }
  } else {
    #pragma unroll
    for (int t = tid; t < 2048; t += 256){
      int r = t >> 4, s8 = (t & 15) * 8;
      int row = rowbase + r;
      if (row < M)
        *reinterpret_cast<bf16x8*>(cs + (size_t)row*512 + colloc + s8) =
            *reinterpret_cast<const bf16x8*>(&smem[r*136 + s8]);
    }
  }
}

// ---------------- attention: 16-lane group per head, 4-deep prefetch ------------
__global__ __launch_bounds__(256) void attn_k(
    const u8* __restrict__ u, const u8* __restrict__ h1f,
    ushort* __restrict__ aggout, float* __restrict__ beta,
    const int* __restrict__ off, const int* __restrict__ csrc)
{
  int lane = threadIdx.x & 63;
  int i = blockIdx.x*4 + (threadIdx.x >> 6);
  int g = lane >> 4;
  int cb = (lane & 15) * 8;

  uint2 uv = *reinterpret_cast<const uint2*>(u + (size_t)i*512 + g*128 + cb);
  f32x2 u01 = __builtin_amdgcn_cvt_pk_f32_fp8(uv.x, false);
  f32x2 u23 = __builtin_amdgcn_cvt_pk_f32_fp8(uv.x, true);
  f32x2 u45 = __builtin_amdgcn_cvt_pk_f32_fp8(uv.y, false);
  f32x2 u67 = __builtin_amdgcn_cvt_pk_f32_fp8(uv.y, true);
  float uf[8] = {u01[0], u01[1], u23[0], u23[1], u45[0], u45[1], u67[0], u67[1]};

  float d = 0.f, agg[8] = {};
  int e0 = off[i], e1 = off[i+1];
  uint2 hA, hB, hC, hD;
  if (e0     < e1) hA = *reinterpret_cast<const uint2*>(h1f + (size_t)csrc[e0]*128 + cb);
  if (e0 + 1 < e1) hB = *reinterpret_cast<const uint2*>(h1f + (size_t)csrc[e0+1]*128 + cb);
  if (e0 + 2 < e1) hC = *reinterpret_cast<const uint2*>(h1f + (size_t)csrc[e0+2]*128 + cb);
  if (e0 + 3 < e1) hD = *reinterpret_cast<const uint2*>(h1f + (size_t)csrc[e0+3]*128 + cb);

  for (int j = e0; j < e1; ++j){
    uint2 hc = hA; hA = hB; hB = hC; hC = hD;
    if (j + 4 < e1) hD = *reinterpret_cast<const uint2*>(h1f + (size_t)csrc[j+4]*128 + cb);
    f32x2 h01 = __builtin_amdgcn_cvt_pk_f32_fp8(hc.x, false);
    f32x2 h23 = __builtin_amdgcn_cvt_pk_f32_fp8(hc.x, true);
    f32x2 h45 = __builtin_amdgcn_cvt_pk_f32_fp8(hc.y, false);
    f32x2 h67 = __builtin_amdgcn_cvt_pk_f32_fp8(hc.y, true);
    float hj[8] = {h01[0], h01[1], h23[0], h23[1], h45[0], h45[1], h67[0], h67[1]};
    float p = uf[0]*hj[0];
    #pragma unroll
    for (int c = 1; c < 8; ++c) p = fmaf(uf[c], hj[c], p);
    p += __shfl_xor(p, 1);
    p += __shfl_xor(p, 2);
    p += __shfl_xor(p, 4);
    p += __shfl_xor(p, 8);                       // intra-16-lane-group reduce
    float a = __expf(p * 0.08838834764831845f);  // logits tiny: no max-shift needed
    d += a;
    #pragma unroll
    for (int c = 0; c < 8; ++c) agg[c] = fmaf(a, hj[c], agg[c]);
  }
  float inv = (d > 0.f) ? 1.f/d : 0.f;
  bf16x8 o;
  #pragma unroll
  for (int c = 0; c < 8; ++c) o[c] = (short)f2bf(agg[c]*inv);
  *reinterpret_cast<bf16x8*>(aggout + (size_t)i*512 + g*128 + cb) = o;
  if ((lane & 15) == 0) beta[i*4 + g] = (d > 0.f) ? 1.f : 0.f;
}

// ---------------- vproj: h2 = relu(s + (agg/d) Wv^h + bv*beta), in-place on s ---
__global__ __launch_bounds__(256) void vproj_k(
    const ushort* __restrict__ agg, const ushort* __restrict__ vT,
    const float* __restrict__ bv, const float* __restrict__ beta,
    ushort* __restrict__ s_io, int M)
{
  __shared__ ushort smem[2*128*72];
  __shared__ float sbeta[128];
  ushort* Asm = smem;
  ushort* Bsm = smem + 128*72;
  int tid = threadIdx.x;
  int lane = tid & 63, wid = tid >> 6;
  int wr = wid >> 1, wc = wid & 1;
  int seg = blockIdx.x;                 // head
  int rowbase = blockIdx.y * 128;
  int lr = lane & 15, lk = (lane >> 4) * 8;
  int rq = lane >> 4;

  if (tid < 128){
    int row = rowbase + tid;
    sbeta[tid] = (row < M) ? beta[row*4 + seg] : 0.f;
  }

  f32x4 acc[4][4] = {};
  for (int k0 = 0; k0 < 128; k0 += 64){
    #pragma unroll
    for (int i = 0; i < 4; ++i){
      int c = tid + i*256;
      int r = c >> 3, col8 = (c & 7) * 8;
      int row = rowbase + r;
      bf16x8 av = (bf16x8)0;
      if (row < M) av = *reinterpret_cast<const bf16x8*>(agg + (size_t)row*512 + seg*128 + k0 + col8);
      *reinterpret_cast<bf16x8*>(&Asm[r*72 + col8]) = av;
      *reinterpret_cast<bf16x8*>(&Bsm[r*72 + col8]) =
          *reinterpret_cast<const bf16x8*>(vT + (size_t)(seg*128 + r)*128 + k0 + col8);
    }
    __syncthreads();
    #pragma unroll
    for (int ks = 0; ks < 64; ks += 32){
      bf16x8 af[4], bfr[4];
      #pragma unroll
      for (int i = 0; i < 4; ++i)
        af[i] = *reinterpret_cast<const bf16x8*>(&Asm[(wr*64 + i*16 + lr)*72 + ks + lk]);
      #pragma unroll
      for (int j = 0; j < 4; ++j)
        bfr[j] = *reinterpret_cast<const bf16x8*>(&Bsm[(wc*64 + j*16 + lr)*72 + ks + lk]);
      #pragma unroll
      for (int i = 0; i < 4; ++i)
        #pragma unroll
        for (int j = 0; j < 4; ++j)
          acc[i][j] = __builtin_amdgcn_mfma_f32_16x16x32_bf16(af[i], bfr[j], acc[i][j], 0, 0, 0);
    }
    __syncthreads();
  }

  #pragma unroll
  for (int i = 0; i < 4; ++i)
    #pragma unroll
    for (int r = 0; r < 4; ++r){
      int lrow = wr*64 + i*16 + rq*4 + r;
      #pragma unroll
      for (int j = 0; j < 4; ++j){
        int lcol = wc*64 + j*16 + lr;
        float v = acc[i][j][r] + bv[seg*128 + lcol] * sbeta[lrow];
        smem[lrow*136 + lcol] = f2bf(v);
      }
    }
  __syncthreads();
  #pragma unroll
  for (int t = tid; t < 2048; t += 256){
    int r = t >> 4, s8 = (t & 15) * 8;
    int row = rowbase + r;
    if (row < M){
      ushort* p = s_io + (size_t)row*512 + seg*128 + s8;
      bf16x8 sv = *reinterpret_cast<const bf16x8*>(p);
      bf16x8 tv = *reinterpret_cast<const bf16x8*>(&smem[r*136 + s8]);
      bf16x8 o;
      #pragma unroll
      for (int q2 = 0; q2 < 8; ++q2)
        o[q2] = (short)f2bf(fmaxf(bf2f((ushort)sv[q2]) + bf2f((ushort)tv[q2]), 0.f));
      *reinterpret_cast<bf16x8*>(p) = o;
    }
  }
}

// ---------------- 64-row-tile bf16 MFMA GEMM (lin1), LDS-staged B ---------------
__global__ __launch_bounds__(256) void bgemm64_k(
    const ushort* __restrict__ A1, int lda1, const ushort* __restrict__ B1T, int K1,
    const float* __restrict__ bias, ushort* __restrict__ C, int M, int N)
{
  __shared__ ushort As[64][72];
  __shared__ ushort Bs[128][72];
  int tid  = threadIdx.x;
  int lane = tid & 63;
  int wid  = tid >> 6;
  int wr = wid >> 1, wc = wid & 1;
  int rowbase = blockIdx.y * 64;
  int colbase = blockIdx.x * 128;
  int lr = lane & 15, lk = (lane >> 4) * 8;

  f32x4 acc[2][4] = {};

  for (int k0 = 0; k0 < K1; k0 += 64){
    #pragma unroll
    for (int i = 0; i < 2; ++i){
      int c = tid + i*256;
      int r = c >> 3, col8 = (c & 7) * 8;
      int row = rowbase + r;
      bf16x8 av = (bf16x8)0;
      if (row < M) av = *reinterpret_cast<const bf16x8*>(A1 + (size_t)row*lda1 + k0 + col8);
      *reinterpret_cast<bf16x8*>(&As[r][col8]) = av;
    }
    #pragma unroll
    for (int i = 0; i < 4; ++i){
      int c = tid + i*256;
      int r = c >> 3, col8 = (c & 7) * 8;
      *reinterpret_cast<bf16x8*>(&Bs[r][col8]) =
          *reinterpret_cast<const bf16x8*>(B1T + (size_t)(colbase + r)*K1 + k0 + col8);
    }
    __syncthreads();
    #pragma unroll
    for (int ks = 0; ks < 64; ks += 32){
      bf16x8 af[2], bfr[4];
      #pragma unroll
      for (int i = 0; i < 2; ++i)
        af[i] = *reinterpret_cast<const bf16x8*>(&As[wr*32 + i*16 + lr][ks + lk]);
      #pragma unroll
      for (int j = 0; j < 4; ++j)
        bfr[j] = *reinterpret_cast<const bf16x8*>(&Bs[wc*64 + j*16 + lr][ks + lk]);
      #pragma unroll
      for (int i = 0; i < 2; ++i)
        #pragma unroll
        for (int j = 0; j < 4; ++j)
          acc[i][j] = __builtin_amdgcn_mfma_f32_16x16x32_bf16(af[i], bfr[j], acc[i][j], 0, 0, 0);
    }
    __syncthreads();
  }

  int rq = lane >> 4;
  #pragma unroll
  for (int i = 0; i < 2; ++i){
    #pragma unroll
    for (int r = 0; r < 4; ++r){
      int row = rowbase + wr*32 + i*16 + rq*4 + r;
      if (row >= M) continue;
      #pragma unroll
      for (int j = 0; j < 4; ++j){
        int col = colbase + wc*64 + j*16 + lr;
        if (col >= N) continue;
        float v = fmaxf(acc[i][j][r] + bias[col], 0.f);
        C[(size_t)row*N + col] = f2bf(v);
      }
    }
  }
}

// ---------------- fused GraphConv: out = relu(h@Wr + agg(h)@Wn + b + h) ---------
__global__ __launch_bounds__(256) void gconv_k(
    const ushort* __restrict__ h, const ushort* __restrict__ WrT,
    const ushort* __restrict__ WnT, const float* __restrict__ bias,
    const int* __restrict__ off, const int* __restrict__ csrc,
    ushort* __restrict__ out, int M)
{
  __shared__ ushort As1[64][136];
  __shared__ ushort As2[64][136];
  int tid = threadIdx.x, lane = tid & 63, wid = tid >> 6;
  int wr = wid >> 1, wc = wid & 1;
  int rowbase = blockIdx.x * 64;
  int lr = lane & 15, lk = (lane >> 4) * 8;

  #pragma unroll
  for (int it = 0; it < 4; ++it){
    int c = tid + it*256;
    int r = c >> 4, col8 = (c & 15) * 8;
    int row = rowbase + r;
    bf16x8 av = (bf16x8)0;
    if (row < M) av = *reinterpret_cast<const bf16x8*>(h + (size_t)row*128 + col8);
    *reinterpret_cast<bf16x8*>(&As1[r][col8]) = av;
  }
  {
    int r = tid >> 2, sl = tid & 3;
    int row = rowbase + r;
    float a[32] = {};
    if (row < M){
      int e1 = off[row+1];
      for (int j = off[row]; j < e1; ++j){
        const ushort* hp = h + (size_t)csrc[j]*128 + sl*32;
        #pragma unroll
        for (int u = 0; u < 4; ++u){
          bf16x8 hv = *reinterpret_cast<const bf16x8*>(hp + u*8);
          #pragma unroll
          for (int p = 0; p < 8; ++p) a[u*8+p] += bf2f((ushort)hv[p]);
        }
      }
    }
    #pragma unroll
    for (int u = 0; u < 4; ++u){
      bf16x8 o;
      #pragma unroll
      for (int p = 0; p < 8; ++p) o[p] = (short)f2bf(a[u*8+p]);
      *reinterpret_cast<bf16x8*>(&As2[r][sl*32 + u*8]) = o;
    }
  }
  __syncthreads();

  f32x4 acc[2][4] = {};
  #pragma unroll
  for (int pass = 0; pass < 2; ++pass){
    const ushort* BT = pass ? WnT : WrT;
    #pragma unroll
    for (int kk = 0; kk < 128; kk += 32){
      bf16x8 af[2], bfr[4];
      #pragma unroll
      for (int i = 0; i < 2; ++i)
        af[i] = pass
          ? *reinterpret_cast<const bf16x8*>(&As2[wr*32 + i*16 + lr][kk + lk])
          : *reinterpret_cast<const bf16x8*>(&As1[wr*32 + i*16 + lr][kk + lk]);
      #pragma unroll
      for (int j = 0; j < 4; ++j)
        bfr[j] = *reinterpret_cast<const bf16x8*>(
            BT + (size_t)(wc*64 + j*16 + lr)*128 + kk + lk);
      #pragma unroll
      for (int i = 0; i < 2; ++i)
        #pragma unroll
        for (int j = 0; j < 4; ++j)
          acc[i][j] = __builtin_amdgcn_mfma_f32_16x16x32_bf16(af[i], bfr[j], acc[i][j], 0, 0, 0);
    }
  }

  int rq = lane >> 4;
  #pragma unroll
  for (int i = 0; i < 2; ++i){
    #pragma unroll
    for (int r = 0; r < 4; ++r){
      int lrow = wr*32 + i*16 + rq*4 + r;
      int row = rowbase + lrow;
      if (row >= M) continue;
      #pragma unroll
      for (int j = 0; j < 4; ++j){
        int col = wc*64 + j*16 + lr;
        float v = acc[i][j][r] + bias[col] + bf2f(As1[lrow][col]);
        out[(size_t)row*128 + col] = f2bf(fmaxf(v, 0.f));
      }
    }
  }
}

// ---------------- pooling stage 1: partial row sums ----------------
__global__ __launch_bounds__(256) void fc1_k(const ushort* __restrict__ h,
                                             float* __restrict__ partial){
  int s = blockIdx.x, c0 = blockIdx.y;
  int t = threadIdx.x;
  int c = t & 127, g = t >> 7;
  float sum = 0.f;
  int rend = (c0 + 1) * 125;
  for (int r = c0*125 + g; r < rend; r += 2)
    sum += bf2f(h[((size_t)s*1625 + r)*128 + c]);
  __shared__ float zs[2][128];
  zs[g][c] = sum; __syncthreads();
  if (g == 0) partial[((size_t)s*13 + c0)*128 + c] = zs[0][c] + zs[1][c];
}

// ---------------- pooling stage 2 + classifier ----------------
__global__ __launch_bounds__(128) void fc2_k(const float* __restrict__ partial,
    const float* __restrict__ fcw, const float* __restrict__ fcb,
    float* __restrict__ out)
{
  int s = blockIdx.x;
  int c = threadIdx.x;
  float z = 0.f;
  #pragma unroll
  for (int p = 0; p < 13; ++p) z += partial[((size_t)s*13 + p)*128 + c];
  __shared__ float zs[128];
  zs[c] = z * (1.0f/1625.0f);
  __syncthreads();
  if (c < 7){
    float o = fcb[c];
    for (int k2 = 0; k2 < 128; ++k2) o = fmaf(zs[k2], fcw[k2*7 + c], o);
    out[s*7 + c] = o;
  }
}

// ---------------- launcher ----------------
extern "C" void kernel_launch(void* const* d_in, const int* in_sizes, int n_in,
                              void* d_out, int out_size, void* d_ws, size_t ws_size,
                              hipStream_t stream)
{
  const float* x     = (const float*)d_in[0];
  const int*   ei    = (const int*)  d_in[1];
  const float* w1r   = (const float*)d_in[3];
  const float* w1n   = (const float*)d_in[4];
  const float* b1    = (const float*)d_in[5];
  const float* wq    = (const float*)d_in[6];
  const float* bq    = (const float*)d_in[7];
  const float* wk    = (const float*)d_in[8];
  const float* wv    = (const float*)d_in[10];
  const float* bv    = (const float*)d_in[11];
  const float* wskip = (const float*)d_in[12];
  const float* bskip = (const float*)d_in[13];
  const float* skw   = (const float*)d_in[14];
  const float* lin1w = (const float*)d_in[15];
  const float* lin1b = (const float*)d_in[16];
  const float* l2r   = (const float*)d_in[17];
  const float* l2n   = (const float*)d_in[18];
  const float* l2b   = (const float*)d_in[19];
  const float* l3r   = (const float*)d_in[20];
  const float* l3n   = (const float*)d_in[21];
  const float* l3b   = (const float*)d_in[22];
  const float* fcw   = (const float*)d_in[23];
  const float* fcb   = (const float*)d_in[24];
  float* out = (float*)d_out;

  const int* src = ei;
  const int* dst = ei + NE;

  char* base = (char*)d_ws;
  size_t o = 0;
  auto alloc = [&](size_t bytes) -> void* {
    o = (o + 255) & ~(size_t)255;
    void* p = base + o; o += bytes; return p;
  };
  int*    cnt     = (int*)   alloc((size_t)NN*4);
  int*    off     = (int*)   alloc((size_t)(NN+1)*4);
  int*    csrc    = (int*)   alloc((size_t)NE*4);
  float*  partial = (float*) alloc((size_t)16*13*128*4);
  float*  bu      = (float*) alloc((size_t)512*4);
  float*  beta    = (float*) alloc((size_t)NN*4*4);
  ushort* h1      = (ushort*)alloc((size_t)NN*128*2);
  u8*     h1f     = (u8*)    alloc((size_t)NN*128);
  ushort* wbuf    = (ushort*)alloc((size_t)327680*2);
  u8*     bufU8   = (u8*)    alloc((size_t)NN*512);     // fp8 u
  ushort* aggbuf  = (ushort*)alloc((size_t)NN*512*2);   // agg/d (bf16)
  ushort* bufS    = (ushort*)alloc((size_t)NN*512*2);   // skip -> h2 -> h5
  ushort* hbuf    = (ushort*)alloc((size_t)NN*256*2);   // h3 | h4
  (void)ws_size; (void)in_sizes; (void)n_in; (void)out_size;

  const ushort* lin1T = wbuf + 131072;
  const ushort* vT    = wbuf + 196608;
  const ushort* l2rT  = wbuf + 262144;
  const ushort* l2nT  = wbuf + 278528;
  const ushort* l3rT  = wbuf + 294912;
  const ushort* l3nT  = wbuf + 311296;

  ushort* h3 = hbuf;
  ushort* h4 = hbuf + (size_t)NN*128;
  ushort* h5 = bufS;

  // CSR + weight prep
  hipMemsetAsync(cnt, 0, (size_t)NN*4, stream);
  mt_k<<<4, 256, 0, stream>>>(wq, wk, bq, wbuf, bu);
  cp_k<<<CNT_BLOCKS + 1024, 256, 0, stream>>>(
      dst, cnt, wv, wskip, skw, lin1w, l2r, l2n, l3r, l3n, wbuf);
  scan_k<<<1, 1024, 0, stream>>>(cnt, off);
  fill_k<<<(NE+255)/256, 256, 0, stream>>>(src, dst, cnt, csrc, NE);

  // layer 1 (fused agg + conv + fp8 cast)
  layer1_k<<<NN/2, 256, 0, stream>>>(x, off, csrc, w1r, w1n, b1, h1, h1f);

  // u | skip projection
  {
    dim3 g(8, (NN+127)/128);
    us_k<<<g, 256, 0, stream>>>(h1, wbuf, bu, bskip, bufU8, bufS, NN);
  }

  // attention: logits via u.h1, aggregate h1 -> aggbuf, beta flags
  attn_k<<<NN/4, 256, 0, stream>>>(bufU8, h1f, aggbuf, beta, off, csrc);

  // vproj: h2 = relu(s + (agg/d)Wv + bv*beta), in-place on bufS
  {
    dim3 g(4, (NN+127)/128);
    vproj_k<<<g, 256, 0, stream>>>(aggbuf, vT, bv, beta, bufS, NN);
  }

  // lin1: h3 = relu(h2 @ lin1_w + lin1_b)
  {
    dim3 g(1, (NN+63)/64);
    bgemm64_k<<<g, 256, 0, stream>>>(bufS, 512, lin1T, 512, lin1b, h3, NN, 128);
  }

  // GraphConv residual layers
  gconv_k<<<(NN+63)/64, 256, 0, stream>>>(h3, l2rT, l2nT, l2b, off, csrc, h4, NN);
  gconv_k<<<(NN+63)/64, 256, 0, stream>>>(h4, l3rT, l3nT, l3b, off, csrc, h5, NN);

  // pool + frame mean + classify
  {
    dim3 g1(16, 13);
    fc1_k<<<g1, 256, 0, stream>>>(h5, partial);
    fc2_k<<<16, 128, 0, stream>>>(partial, fcw, fcb, out);
  }
}